// Round 10
// baseline (500.978 us; speedup 1.0000x reference)
//
#include <hip/hip_runtime.h>

typedef _Float16 f16;
typedef _Float16 f16x2 __attribute__((ext_vector_type(2)));
typedef _Float16 f16x4 __attribute__((ext_vector_type(4)));
typedef _Float16 f16x8 __attribute__((ext_vector_type(8)));
typedef float f32x16 __attribute__((ext_vector_type(16)));

#define DEV __device__ __forceinline__
#define MFMA16(a, b, cc) __builtin_amdgcn_mfma_f32_32x32x16_f16(a, b, cc, 0, 0, 0)

// ---------------- problem constants ----------------
// B=131072, LATENT=32, COND=96, INPUT=128, HIDDEN=128, OUT=64, E=8, GH=128, INTER=160

// workspace (f16 element offsets) — packed weight fragments
constexpr int OFF_W0 = 0;        // 8 experts * S8  * CT4 * 64 * 8 = 131072
constexpr int OFF_W1 = 131072;   // 8 * S10 * CT4 * 64 * 8 = 163840
constexpr int OFF_W2 = 294912;   // 163840
constexpr int OFF_W3 = 458752;   // 8 * S10 * CT2 * 64 * 8 = 81920
constexpr int OFF_G0 = 540672;   // S8 * CT4 * 64 * 8 = 16384
constexpr int OFF_G1 = 557056;   // 16384
constexpr int OFF_B0 = 573440;   // CT4 * 64 * 8 = 2048
constexpr int OFF_B1 = 575488;
constexpr int OFF_B2 = 577536;
constexpr int OFF_B3 = 579584;   // CT2 * 64 * 8 = 1024

// ---------------- weight repack kernel (unchanged) ----------------
// packed[e][s][ct][lane][i] = w[e][s*16 + (lane>>5)*8 + i][ct*32 + (lane&31)]
__global__ __launch_bounds__(256) void repack_kernel(
    const float* __restrict__ w0, const float* __restrict__ w1,
    const float* __restrict__ w2, const float* __restrict__ w3,
    const float* __restrict__ gw0, const float* __restrict__ gw1,
    const float* __restrict__ b0, const float* __restrict__ b1,
    const float* __restrict__ b2, const float* __restrict__ b3,
    f16* __restrict__ ws)
{
  int g = blockIdx.x * 256 + threadIdx.x;
  if (g < 71680) {
    const float* src; int S, CT, K, dstoff, lg;
    if (g < 16384)      { src = w0;  S = 8;  CT = 4; K = 128; dstoff = OFF_W0; lg = g; }
    else if (g < 36864) { src = w1;  S = 10; CT = 4; K = 128; dstoff = OFF_W1; lg = g - 16384; }
    else if (g < 57344) { src = w2;  S = 10; CT = 4; K = 128; dstoff = OFF_W2; lg = g - 36864; }
    else if (g < 67584) { src = w3;  S = 10; CT = 2; K = 64;  dstoff = OFF_W3; lg = g - 57344; }
    else if (g < 69632) { src = gw0; S = 8;  CT = 4; K = 128; dstoff = OFF_G0; lg = g - 67584; }
    else                { src = gw1; S = 8;  CT = 4; K = 128; dstoff = OFF_G1; lg = g - 69632; }
    int l = lg & 63;
    int t = lg >> 6;
    int ct = t % CT; t /= CT;
    int s = t % S;
    int e = t / S;
    int J = S * 16;
    int n  = ct * 32 + (l & 31);
    int jb = s * 16 + (l >> 5) * 8;
    f16* dst = ws + dstoff + (size_t)lg * 8;
#pragma unroll
    for (int i = 0; i < 8; ++i)
      dst[i] = (f16)src[((size_t)(e * J + jb + i)) * K + n];
  } else if (g < 72576) {
    int bg = g - 71680;
    const float* src; int K, dstoff, lb;
    if (bg < 256)      { src = b0; K = 128; dstoff = OFF_B0; lb = bg; }
    else if (bg < 512) { src = b1; K = 128; dstoff = OFF_B1; lb = bg - 256; }
    else if (bg < 768) { src = b2; K = 128; dstoff = OFF_B2; lb = bg - 512; }
    else               { src = b3; K = 64;  dstoff = OFF_B3; lb = bg - 768; }
    int l = lb & 63, ct = lb >> 6;
    int n = ct * 32 + (l & 31);
    f16* dst = ws + dstoff + (size_t)lb * 8;
#pragma unroll
    for (int i = 0; i < 8; ++i)
      dst[i] = (l < 32) ? (f16)src[i * K + n] : (f16)0.0f;
  }
}

// ---------------- fused kernel helpers ----------------
// swizzled activation LDS: fp16 [128 rows][128 cols], pitch 256B.
DEV unsigned char* actsp(unsigned char* acts, int row, int colb) {
  return acts + (((row << 8) + colb) ^ ((row & 15) << 4));
}

DEV f16x8 cvt8(float4 a, float4 b) {
  f16x8 r;
  r[0] = (f16)a.x; r[1] = (f16)a.y; r[2] = (f16)a.z; r[3] = (f16)a.w;
  r[4] = (f16)b.x; r[5] = (f16)b.y; r[6] = (f16)b.z; r[7] = (f16)b.w;
  return r;
}

// per-row mean/rsqrt(var+eps); lane l and l^32 hold complementary j-halves
// of the same row -> one shfl_xor(32) completes the row.
template <int NF>
DEV void rowstats(const f16x8 (&F)[NF], float invJ, float& mu, float& rs) {
  float s1 = 0.f, s2 = 0.f;
#pragma unroll
  for (int i = 0; i < NF; ++i)
#pragma unroll
    for (int q = 0; q < 8; ++q) {
      float v = (float)F[i][q];
      s1 += v;
      s2 += v * v;
    }
  s1 += __shfl_xor(s1, 32, 64);
  s2 += __shfl_xor(s2, 32, 64);
  mu = s1 * invJ;
  float var = s2 * invJ - mu * mu;
  rs = rsqrtf(var + 1e-5f);
}

// expert loop: FULLY unrolled (static cf[e] indexing, static ping-pong).
// Per wave: one 32-row tile (F[NS]) x NCTW 32-col tiles.
template <int NS, int NCTW, int CTTOT, int N16>
DEV void expert_loop(const f16x8 (&F)[NS], float mu, float rs,
                     unsigned char* wb0, unsigned char* wb1,
                     const f16x8 cf,
                     const f16* wsrc, const f16* nextsrc, int next_n16,
                     int ct0, int lane, int tid,
                     f32x16 (&acc)[NCTW]) {
#pragma unroll
  for (int e = 0; e < 8; ++e) {
    unsigned char* rb  = (e & 1) ? wb1 : wb0;
    unsigned char* wbn = (e & 1) ? wb0 : wb1;
    const float4* src = (const float4*)((e < 7) ? (wsrc + (size_t)(e + 1) * N16 * 8) : nextsrc);
    int n16 = (e < 7) ? N16 : next_n16;
    float4 stg[5];
#pragma unroll
    for (int k = 0; k < 5; ++k) {
      int idx = tid + k * 512;
      if (idx < n16) stg[k] = src[idx];
    }
    float pf = rs * (float)cf[e];
    f16 p = (f16)pf, q = (f16)(-mu * pf);
#pragma unroll
    for (int s = 0; s < NS; ++s) {
      f16x8 a = F[s] * p + q;
#pragma unroll
      for (int t = 0; t < NCTW; ++t) {
        f16x8 b = *(const f16x8*)(rb + (size_t)(((s * CTTOT) + (ct0 + t)) * 64 + lane) * 16);
        acc[t] = MFMA16(a, b, acc[t]);
      }
    }
#pragma unroll
    for (int k = 0; k < 5; ++k) {
      int idx = tid + k * 512;
      if (idx < n16) *(float4*)(wbn + (size_t)idx * 16) = stg[k];
    }
    __syncthreads();
  }
}

// mixed_bias = coeff @ b as one extra MFMA (k>=8 rows of B are zero-packed)
template <int NCTW>
DEV void bias_mfma(f32x16 (&acc)[NCTW], const f16x8 cf, const f16* pb,
                   int ct0, int lane) {
#pragma unroll
  for (int t = 0; t < NCTW; ++t) {
    f16x8 bb = *(const f16x8*)(pb + (size_t)((ct0 + t) * 64 + lane) * 8);
    acc[t] = MFMA16(cf, bb, acc[t]);
  }
}

template <int NCTW>
DEV void store_acts(const f32x16 (&acc)[NCTW], unsigned char* acts,
                    int wrow, int ct0, int lr, int h) {
#pragma unroll
  for (int t = 0; t < NCTW; ++t) {
    int col = (ct0 + t) * 32 + lr;
#pragma unroll
    for (int r = 0; r < 16; ++r) {
      float v = acc[t][r];
      v = v > 0.f ? v : __expf(v) - 1.f;   // ELU
      int rowl = (r & 3) + 8 * (r >> 2) + 4 * h;
      *(f16*)actsp(acts, wrow * 32 + rowl, col * 2) = (f16)v;
    }
  }
}

// ---------------- fused decoder kernel ----------------
// 128-row tile / block, 512 threads (8 waves), wave = 32x64 output tile.
// Sized so arch-VGPR demand (~100) fits the 128-reg budget of a 2-wave/SIMD
// workgroup -- the 256-row version spilled ~250 MB of scratch per launch.
__global__ __launch_bounds__(512, 2) void moe_fused(
    const float* __restrict__ z, const float* __restrict__ c,
    const float* __restrict__ gb0, const float* __restrict__ gb1,
    const float* __restrict__ gw2, const float* __restrict__ gb2,
    const f16* __restrict__ ws, float* __restrict__ out)
{
  __shared__ __align__(16) unsigned char smem[116736];
  unsigned char* wb0  = smem;                 // 40960: weight ping
  unsigned char* wb1  = smem + 40960;         // 40960: weight pong
  unsigned char* acts = smem + 81920;         // 32768: fp16 [128][128] swizzled
  f16* coeffH = (f16*)(smem + 114688);        // [128][8] fp16 (2048 B)

  const int tid  = threadIdx.x;
  const int lane = tid & 63;
  const int wave = tid >> 6;
  const int wrow = wave >> 1, wc = wave & 1;
  const int h = lane >> 5, lr = lane & 31;
  const int brow = blockIdx.x << 7;
  const int lrow = wrow * 32 + lr;
  const int ct0 = wc * 2;

  // ---- stage x = [z|c] as fp16 into acts (4 threads/row, 32 cols each) ----
  {
    int row = tid >> 2, q4 = tid & 3;
    const float* zr = z + (size_t)(brow + row) * 32;
    const float* cr = c + (size_t)(brow + row) * 96;
#pragma unroll
    for (int jj = 0; jj < 8; ++jj) {
      int j0 = q4 * 32 + jj * 4;
      float4 v = (j0 < 32) ? *(const float4*)(zr + j0)
                           : *(const float4*)(cr + (j0 - 32));
      f16x4 hv = {(f16)v.x, (f16)v.y, (f16)v.z, (f16)v.w};
      *(f16x4*)actsp(acts, row, j0 * 2) = hv;
    }
  }
  float4 stgA[4];
  { // issue gw0
    const float4* g4 = (const float4*)(ws + OFF_G0);
#pragma unroll
    for (int k = 0; k < 4; ++k) stgA[k] = g4[tid + k * 512];
  }
  __syncthreads();  // x ready

  // ---- commit gw0; read x fragments; LN(x) stats (kept for layer 0) ----
#pragma unroll
  for (int k = 0; k < 4; ++k) *(float4*)(wb0 + (size_t)(tid + k * 512) * 16) = stgA[k];
  f16x8 FX[8];
#pragma unroll
  for (int s = 0; s < 8; ++s)
    FX[s] = *(const f16x8*)actsp(acts, lrow, s * 32 + h * 16);
  float muX, rsX;
  rowstats<8>(FX, 1.f / 128.f, muX, rsX);
  { // issue gw1
    const float4* g4 = (const float4*)(ws + OFF_G1);
#pragma unroll
    for (int k = 0; k < 4; ++k) stgA[k] = g4[tid + k * 512];
  }
  __syncthreads();  // gw0 ready; all x-fragment reads done

  // ---- gate GEMM1: h = elu(x @ gw0 + gb0) ----
  f32x16 acc[2];
#pragma unroll
  for (int t = 0; t < 2; ++t)
#pragma unroll
    for (int i = 0; i < 16; ++i) acc[t][i] = 0.f;
#pragma unroll
  for (int s = 0; s < 8; ++s) {
    f16x8 b0 = *(const f16x8*)(wb0 + (size_t)((s * 4 + ct0) * 64 + lane) * 16);
    f16x8 b1 = *(const f16x8*)(wb0 + (size_t)((s * 4 + ct0 + 1) * 64 + lane) * 16);
    acc[0] = MFMA16(FX[s], b0, acc[0]);
    acc[1] = MFMA16(FX[s], b1, acc[1]);
  }
#pragma unroll
  for (int t = 0; t < 2; ++t) {
    int col = (ct0 + t) * 32 + lr;
    float bias = gb0[col];
#pragma unroll
    for (int r = 0; r < 16; ++r) {
      float v = acc[t][r] + bias;
      v = v > 0.f ? v : __expf(v) - 1.f;
      int rowl = (r & 3) + 8 * (r >> 2) + 4 * h;
      *(f16*)actsp(acts, wrow * 32 + rowl, col * 2) = (f16)v;
    }
  }
#pragma unroll
  for (int k = 0; k < 4; ++k) *(float4*)(wb1 + (size_t)(tid + k * 512) * 16) = stgA[k];
  __syncthreads();  // h ready; gw1 ready

  // ---- gate GEMM2: h2 = elu(h @ gw1 + gb1) ----
#pragma unroll
  for (int t = 0; t < 2; ++t)
#pragma unroll
    for (int i = 0; i < 16; ++i) acc[t][i] = 0.f;
#pragma unroll
  for (int s = 0; s < 8; ++s) {
    f16x8 a = *(const f16x8*)actsp(acts, lrow, s * 32 + h * 16);
    f16x8 b0 = *(const f16x8*)(wb1 + (size_t)((s * 4 + ct0) * 64 + lane) * 16);
    f16x8 b1 = *(const f16x8*)(wb1 + (size_t)((s * 4 + ct0 + 1) * 64 + lane) * 16);
    acc[0] = MFMA16(a, b0, acc[0]);
    acc[1] = MFMA16(a, b1, acc[1]);
  }
  { // issue w0 expert0
    const float4* g4 = (const float4*)(ws + OFF_W0);
#pragma unroll
    for (int k = 0; k < 4; ++k) stgA[k] = g4[tid + k * 512];
  }
  __syncthreads();  // all h reads done
#pragma unroll
  for (int t = 0; t < 2; ++t) {
    int col = (ct0 + t) * 32 + lr;
    float bias = gb1[col];
#pragma unroll
    for (int r = 0; r < 16; ++r) {
      float v = acc[t][r] + bias;
      v = v > 0.f ? v : __expf(v) - 1.f;
      int rowl = (r & 3) + 8 * (r >> 2) + 4 * h;
      *(f16*)actsp(acts, wrow * 32 + rowl, col * 2) = (f16)v;
    }
  }
#pragma unroll
  for (int k = 0; k < 4; ++k) *(float4*)(wb0 + (size_t)(tid + k * 512) * 16) = stgA[k];
  __syncthreads();  // h2 ready; w0e0 ready

  // ---- gate GEMM3 (K=8, VALU, 4 threads/row) + softmax -> coeff ----
  {
    int row = tid >> 2, part = tid & 3;
    float lgt[8];
#pragma unroll
    for (int e = 0; e < 8; ++e) lgt[e] = 0.f;
#pragma unroll
    for (int qq = 0; qq < 4; ++qq) {
      f16x8 hv = *(const f16x8*)actsp(acts, row, part * 64 + qq * 16);
#pragma unroll
      for (int i = 0; i < 8; ++i) {
        float hf = (float)hv[i];
        int j = part * 32 + qq * 8 + i;
        const float4* gp = (const float4*)(gw2 + j * 8);
        float4 ga = gp[0], gb = gp[1];
        lgt[0] += hf * ga.x; lgt[1] += hf * ga.y; lgt[2] += hf * ga.z; lgt[3] += hf * ga.w;
        lgt[4] += hf * gb.x; lgt[5] += hf * gb.y; lgt[6] += hf * gb.z; lgt[7] += hf * gb.w;
      }
    }
#pragma unroll
    for (int e = 0; e < 8; ++e) {
      lgt[e] += __shfl_xor(lgt[e], 1, 64);
      lgt[e] += __shfl_xor(lgt[e], 2, 64);
      lgt[e] += gb2[e];
    }
    float m = lgt[0];
#pragma unroll
    for (int e = 1; e < 8; ++e) m = fmaxf(m, lgt[e]);
    float ssum = 0.f, pe[8];
#pragma unroll
    for (int e = 0; e < 8; ++e) { pe[e] = __expf(lgt[e] - m); ssum += pe[e]; }
    float inv = 1.f / ssum;
    if (part == 0) {
      f16x8 ch;
#pragma unroll
      for (int e = 0; e < 8; ++e) ch[e] = (f16)(pe[e] * inv);
      *(f16x8*)(coeffH + row * 8) = ch;
    }
  }
  __syncthreads();  // coeff ready

  const f16x8 cf = *(const f16x8*)(coeffH + lrow * 8);

  // ---- layer 0: inp = LN(x), J=128 (x frags + stats still in regs) ----
#pragma unroll
  for (int t = 0; t < 2; ++t)
#pragma unroll
    for (int i = 0; i < 16; ++i) acc[t][i] = 0.f;
  expert_loop<8, 2, 4, 2048>(FX, muX, rsX, wb0, wb1, cf,
                             ws + OFF_W0, ws + OFF_W1, 2560,
                             ct0, lane, tid, acc);
  bias_mfma<2>(acc, cf, ws + OFF_B0, ct0, lane);
  store_acts<2>(acc, acts, wrow, ct0, lr, h);
  __syncthreads();  // layer0 out complete; w1e0 staged

  // ---- layers 1..3: inp = LN([z | prev]), J=160 ----
  f16x8 F[10];
  float mu, rs;
  auto load_layer_frags = [&]() {
#pragma unroll
    for (int s = 0; s < 2; ++s) {  // z part from global (L2-resident)
      const float* zp = z + (size_t)(brow + lrow) * 32 + s * 16 + h * 8;
      float4 a0 = *(const float4*)zp, a1 = *(const float4*)(zp + 4);
      F[s] = cvt8(a0, a1);
    }
#pragma unroll
    for (int s = 0; s < 8; ++s)
      F[2 + s] = *(const f16x8*)actsp(acts, lrow, s * 32 + h * 16);
    rowstats<10>(F, 1.f / 160.f, mu, rs);
  };

  // layer 1
  load_layer_frags();
#pragma unroll
  for (int t = 0; t < 2; ++t)
#pragma unroll
    for (int i = 0; i < 16; ++i) acc[t][i] = 0.f;
  expert_loop<10, 2, 4, 2560>(F, mu, rs, wb0, wb1, cf,
                              ws + OFF_W1, ws + OFF_W2, 2560,
                              ct0, lane, tid, acc);
  bias_mfma<2>(acc, cf, ws + OFF_B1, ct0, lane);
  store_acts<2>(acc, acts, wrow, ct0, lr, h);
  __syncthreads();

  // layer 2
  load_layer_frags();
#pragma unroll
  for (int t = 0; t < 2; ++t)
#pragma unroll
    for (int i = 0; i < 16; ++i) acc[t][i] = 0.f;
  expert_loop<10, 2, 4, 2560>(F, mu, rs, wb0, wb1, cf,
                              ws + OFF_W2, ws + OFF_W3, 1280,
                              ct0, lane, tid, acc);
  bias_mfma<2>(acc, cf, ws + OFF_B2, ct0, lane);
  store_acts<2>(acc, acts, wrow, ct0, lr, h);
  __syncthreads();

  // layer 3 (K=64, no activation, fp32 out)
  load_layer_frags();
  f32x16 acc3[1];
#pragma unroll
  for (int i = 0; i < 16; ++i) acc3[0][i] = 0.f;
  expert_loop<10, 1, 2, 1280>(F, mu, rs, wb0, wb1, cf,
                              ws + OFF_W3, ws /*dummy*/, 0,
                              wc, lane, tid, acc3);
  bias_mfma<1>(acc3, cf, ws + OFF_B3, wc, lane);
  {
    int col = wc * 32 + lr;
#pragma unroll
    for (int r = 0; r < 16; ++r) {
      int rowl = (r & 3) + 8 * (r >> 2) + 4 * h;
      int grow = brow + wrow * 32 + rowl;
      out[(size_t)grow * 64 + col] = acc3[0][r];
    }
  }
}

// ---------------- launch ----------------
extern "C" void kernel_launch(void* const* d_in, const int* in_sizes, int n_in,
                              void* d_out, int out_size, void* d_ws, size_t ws_size,
                              hipStream_t stream) {
  (void)in_sizes; (void)n_in; (void)out_size; (void)ws_size;
  const float* z   = (const float*)d_in[0];
  const float* c   = (const float*)d_in[1];
  const float* w0  = (const float*)d_in[2];
  const float* b0  = (const float*)d_in[3];
  const float* w1  = (const float*)d_in[4];
  const float* b1  = (const float*)d_in[5];
  const float* w2  = (const float*)d_in[6];
  const float* b2  = (const float*)d_in[7];
  const float* w3  = (const float*)d_in[8];
  const float* b3  = (const float*)d_in[9];
  const float* gw0 = (const float*)d_in[10];
  const float* gb0 = (const float*)d_in[11];
  const float* gw1 = (const float*)d_in[12];
  const float* gb1 = (const float*)d_in[13];
  const float* gw2 = (const float*)d_in[14];
  const float* gb2 = (const float*)d_in[15];
  f16* ws = (f16*)d_ws;
  float* out = (float*)d_out;

  repack_kernel<<<dim3(284), dim3(256), 0, stream>>>(
      w0, w1, w2, w3, gw0, gw1, b0, b1, b2, b3, ws);
  moe_fused<<<dim3(1024), dim3(512), 0, stream>>>(
      z, c, gb0, gb1, gw2, gb2, ws, out);
}